// Round 1
// baseline (85.563 us; speedup 1.0000x reference)
//
#include <hip/hip_runtime.h>

// MMDDistance: multi-scale Gaussian MMD.
// support [4,5,196,64] f32, query [4,75,196,64] f32 -> out [4,75,5] f32.
// alphas = 2^k, k=-3..1 -> exp chain via repeated squaring of exp(-0.125*d2).

typedef __attribute__((ext_vector_type(8))) short short8;
typedef __attribute__((ext_vector_type(4))) float f32x4;

#define B_   4
#define NS_  5
#define NQ_  75
#define NF_  196
#define C_   64
#define NROW 208        // 13*16 padded rows
#define PITCH 64        // shorts per row (128 B)
#define NTILE 13
#define NTT  (NTILE*NTILE)  // 169 MFMA tiles

// fp32 -> bf16 round-to-nearest-even (bias-free; truncation would bias d2 by ~0.13)
__device__ __forceinline__ short f2bf(float x) {
  unsigned u = __float_as_uint(x);
  u += 0x7fffu + ((u >> 16) & 1u);
  return (short)(u >> 16);
}
__device__ __forceinline__ float bf2f(short s) {
  return __uint_as_float(((unsigned)(unsigned short)s) << 16);
}

// MODE 0: self-kernel (SS for bid<20, QQ otherwise), skip diagonal, write ws[bid].
// MODE 1: cross-kernel (SQ), read ws, write final out[bid].
template<int MODE>
__global__ __launch_bounds__(256, 2) void mmd_pair_kernel(
    const float* __restrict__ sup, const float* __restrict__ qry,
    float* __restrict__ ws, float* __restrict__ out) {
  constexpr int NARR = (MODE == 1) ? 2 : 1;
  __shared__ short sbuf[NARR * NROW * PITCH];
  __shared__ float n2buf[NARR * NROW];
  __shared__ float redbuf[4];

  const int bid = blockIdx.x;
  const int tid = threadIdx.x;

  const float* xb;
  const float* yb;
  if (MODE == 0) {
    xb = (bid < B_ * NS_) ? (sup + (size_t)bid * (NF_ * C_))
                          : (qry + (size_t)(bid - B_ * NS_) * (NF_ * C_));
    yb = xb;
  } else {
    int s = bid % NS_;
    int q = (bid / NS_) % NQ_;
    int b = bid / (NS_ * NQ_);
    xb = sup + (size_t)(b * NS_ + s) * (NF_ * C_);
    yb = qry + (size_t)(b * NQ_ + q) * (NF_ * C_);
  }

  // ---- stage: fp32 -> bf16 (RNE) into LDS, XOR-swizzled 16B chunks ----
  // swizzle: 16B-chunk index c -> c ^ (row&7); spreads a wave's 64 b128
  // accesses exactly 8 per bank-quad (conflict-free floor).
  const int CHUNKS = NROW * 8;
  for (int f = tid; f < NARR * CHUNKS; f += 256) {
    int arr = f / CHUNKS;
    int g = f - arr * CHUNKS;
    int row = g >> 3, c = g & 7;
    short8 v = {0, 0, 0, 0, 0, 0, 0, 0};
    if (row < NF_) {
      const float* src = (arr ? yb : xb) + row * C_ + c * 8;
      float4 v0 = ((const float4*)src)[0];
      float4 v1 = ((const float4*)src)[1];
      v[0] = f2bf(v0.x); v[1] = f2bf(v0.y); v[2] = f2bf(v0.z); v[3] = f2bf(v0.w);
      v[4] = f2bf(v1.x); v[5] = f2bf(v1.y); v[6] = f2bf(v1.z); v[7] = f2bf(v1.w);
    }
    int dst = arr * (NROW * PITCH) + row * PITCH + (((c * 8) ^ ((row & 7) << 3)));
    *(short8*)&sbuf[dst] = v;
  }
  __syncthreads();

  // ---- n2 per row (from the bf16 values, fp32 accumulate; pad rows = 1e30) ----
  for (int j = tid; j < NARR * NROW; j += 256) {
    int arr = j / NROW, row = j - arr * NROW;
    float acc = 1e30f;
    if (row < NF_) {
      acc = 0.f;
      int base = arr * (NROW * PITCH) + row * PITCH;
      int sw = (row & 7) << 3;
#pragma unroll
      for (int c = 0; c < 8; ++c) {
        short8 vv = *(short8*)&sbuf[base + (((c * 8) ^ sw))];
#pragma unroll
        for (int e = 0; e < 8; ++e) { float x = bf2f(vv[e]); acc = fmaf(x, x, acc); }
      }
    }
    n2buf[j] = acc;
  }
  __syncthreads();

  // ---- main: each wave takes a contiguous range of the 169 tiles ----
  const int w = tid >> 6, l = tid & 63;
  const int lr = l & 15;  // frag row-in-tile; also D col
  const int lg = l >> 4;  // k-group; D row-group
  const int t0 = (NTT * w) / 4, t1 = (NTT * (w + 1)) / 4;
  const int bbase = (MODE == 1) ? NROW * PITCH : 0;
  const int bn2 = (MODE == 1) ? NROW : 0;
  constexpr float K2E = -0.18033688011112042f;  // -0.125 * log2(e)

  float ksum = 0.f;
  int curti = -1;
  short8 a0 = {0,0,0,0,0,0,0,0}, a1 = {0,0,0,0,0,0,0,0};
  float n2s0 = 0.f, n2s1 = 0.f, n2s2 = 0.f, n2s3 = 0.f;

  for (int t = t0; t < t1; ++t) {
    int ti = t / NTILE, tj = t - ti * NTILE;
    if (ti != curti) {
      curti = ti;
      int arow = ti * 16 + lr;
      int sw = (arow & 7) << 3;
      const short* ap = &sbuf[arow * PITCH];
      a0 = *(const short8*)&ap[((lg * 8) ^ sw)];
      a1 = *(const short8*)&ap[((32 + lg * 8) ^ sw)];
      int ib = ti * 16 + lg * 4;
      n2s0 = n2buf[ib + 0]; n2s1 = n2buf[ib + 1];
      n2s2 = n2buf[ib + 2]; n2s3 = n2buf[ib + 3];
    }
    int brow = tj * 16 + lr;
    int swb = (brow & 7) << 3;
    const short* bp = &sbuf[bbase + brow * PITCH];
    short8 b0 = *(const short8*)&bp[((lg * 8) ^ swb)];
    short8 b1 = *(const short8*)&bp[((32 + lg * 8) ^ swb)];
    float n2q = n2buf[bn2 + tj * 16 + lr];

    f32x4 acc = {0.f, 0.f, 0.f, 0.f};
    acc = __builtin_amdgcn_mfma_f32_16x16x32_bf16(a0, b0, acc, 0, 0, 0);
    acc = __builtin_amdgcn_mfma_f32_16x16x32_bf16(a1, b1, acc, 0, 0, 0);

#pragma unroll
    for (int e = 0; e < 4; ++e) {
      float n2s = (e == 0) ? n2s0 : (e == 1) ? n2s1 : (e == 2) ? n2s2 : n2s3;
      float d2 = fmaf(-2.f, acc[e], n2s + n2q);
      d2 = fmaxf(d2, 0.f);
      float e1 = exp2f(d2 * K2E);      // exp(-0.125*d2)
      float e2 = e1 * e1;              // alpha = 0.25
      float e3 = e2 * e2;              // alpha = 0.5
      float e4 = e3 * e3;              // alpha = 1.0
      float e5 = e4 * e4;              // alpha = 2.0
      float kv = ((e1 + e2) + (e3 + e4)) + e5;
      if (MODE == 0) {
        if (ti == tj && (lg * 4 + e) == lr) kv = 0.f;  // skip i==j exactly
      }
      ksum += kv;
    }
  }

  // ---- reduce 256 lanes -> scalar ----
#pragma unroll
  for (int off = 32; off > 0; off >>= 1) ksum += __shfl_xor(ksum, off);
  if (l == 0) redbuf[w] = ksum;
  __syncthreads();
  if (tid == 0) {
    float s = (redbuf[0] + redbuf[1]) + (redbuf[2] + redbuf[3]);
    if (MODE == 0) {
      ws[bid] = s * (0.2f / (196.f * 195.f));  // off-diagonal mean, /5 alphas
    } else {
      int si = bid % NS_;
      int q = (bid / NS_) % NQ_;
      int b = bid / (NS_ * NQ_);
      float msq = s * (0.2f / (196.f * 196.f));
      out[bid] = (ws[b * NS_ + si] + ws[B_ * NS_ + b * NQ_ + q] - 2.f * msq) * 12.5f;
    }
  }
}

extern "C" void kernel_launch(void* const* d_in, const int* in_sizes, int n_in,
                              void* d_out, int out_size, void* d_ws, size_t ws_size,
                              hipStream_t stream) {
  const float* sup = (const float*)d_in[0];
  const float* qry = (const float*)d_in[1];
  float* out = (float*)d_out;
  float* ws = (float*)d_ws;  // 320 floats: mmd_s[20], mmd_q[300]

  // K1: SS (20) + QQ (300) self-kernels -> ws
  mmd_pair_kernel<0><<<dim3(B_ * NS_ + B_ * NQ_), dim3(256), 0, stream>>>(sup, qry, ws, nullptr);
  // K2: SQ cross-kernels -> final out (stream-ordered after K1)
  mmd_pair_kernel<1><<<dim3(B_ * NQ_ * NS_), dim3(256), 0, stream>>>(sup, qry, ws, out);
}

// Round 2
// 82.329 us; speedup vs baseline: 1.0393x; 1.0393x over previous
//
#include <hip/hip_runtime.h>

// MMDDistance: multi-scale Gaussian MMD.
// support [4,5,196,64] f32, query [4,75,196,64] f32 -> out [4,75,5] f32.
// alphas = 2^k, k=-3..1 -> exp chain via repeated squaring of exp(-0.125*d2).
//
// K1 (640 blocks): self-kernels SS (20 pairs) + QQ (300 pairs), 2 partial
//     blocks each, results -> ws[640] (pre-scaled partial means).
// K2 (1500 blocks): SQ cross-kernels; query staged bf16 in LDS (28 KB ->
//     5 blocks/CU), support A-frags converted from global fp32 in registers;
//     writes final out directly.

typedef __attribute__((ext_vector_type(8))) short short8;
typedef __attribute__((ext_vector_type(4))) float f32x4;
typedef __attribute__((ext_vector_type(2))) float f32x2;

#define NF_  196
#define C_   64
#define NROW 208        // 13*16 padded rows
#define NTILE 13
#define NTT  (NTILE*NTILE)

// K2E = -0.125*log2(e); per-row m2 = K2E*n2; t = (-2*K2E)*dot + m2a + m2b
#define K2E_  (-0.18033688011112042f)
#define NEG2K2E_ (0.36067376022224085f)

// fp32 -> bf16 round-to-nearest-even (bias-free)
__device__ __forceinline__ short f2bf(float x) {
  unsigned u = __float_as_uint(x);
  u += 0x7fffu + ((u >> 16) & 1u);
  return (short)(u >> 16);
}
__device__ __forceinline__ float bf2f(short s) {
  return __uint_as_float(((unsigned)(unsigned short)s) << 16);
}
__device__ __forceinline__ short8 pack8(float4 a, float4 b) {
  short8 v;
  v[0] = f2bf(a.x); v[1] = f2bf(a.y); v[2] = f2bf(a.z); v[3] = f2bf(a.w);
  v[4] = f2bf(b.x); v[5] = f2bf(b.y); v[6] = f2bf(b.z); v[7] = f2bf(b.w);
  return v;
}

// stage one [196,64] fp32 array as bf16 into LDS, 16B-chunk XOR swizzle,
// rows 196..207 zero-padded.
__device__ __forceinline__ void stage_bf16(const float* __restrict__ src,
                                           short* __restrict__ sb, int tid) {
  for (int g = tid; g < NROW * 8; g += 256) {
    int row = g >> 3, c = g & 7;
    short8 v = {0, 0, 0, 0, 0, 0, 0, 0};
    if (row < NF_) {
      const float4* s4 = (const float4*)(src + row * C_ + c * 8);
      v = pack8(s4[0], s4[1]);
    }
    *(short8*)&sb[row * C_ + (((c * 8) ^ ((row & 7) << 3)))] = v;
  }
}

// m2[row] = K2E * sum(bf16(x)^2) from the staged LDS values; pad rows -> -1.8e29
__device__ __forceinline__ void m2_from_lds(const short* __restrict__ sb,
                                            float* __restrict__ m2, int tid) {
  for (int row = tid; row < NROW; row += 256) {
    float acc = 1e30f;
    if (row < NF_) {
      acc = 0.f;
      int sw = (row & 7) << 3;
      const short* bp = &sb[row * C_];
#pragma unroll
      for (int c = 0; c < 8; ++c) {
        short8 vv = *(const short8*)&bp[((c * 8) ^ sw)];
#pragma unroll
        for (int e = 0; e < 8; ++e) { float x = bf2f(vv[e]); acc = fmaf(x, x, acc); }
      }
    }
    m2[row] = K2E_ * acc;
  }
}

// multi-gauss kernel values for 4 accumulator elems (as 2 f32x2 pairs)
__device__ __forceinline__ void kpair(const f32x4 acc, f32x2 ms01, f32x2 ms23,
                                      float m2qv, f32x2& kva, f32x2& kvb) {
  f32x2 mq = {m2qv, m2qv};
  f32x2 a01 = {acc[0], acc[1]}, a23 = {acc[2], acc[3]};
  f32x2 zz = {0.f, 0.f};
  f32x2 t01 = a01 * NEG2K2E_ + (ms01 + mq);   // = K2E * d2  (<= 0 ideally)
  f32x2 t23 = a23 * NEG2K2E_ + (ms23 + mq);
  t01 = __builtin_elementwise_min(t01, zz);    // clamp d2 >= 0
  t23 = __builtin_elementwise_min(t23, zz);
  f32x2 E1a = {__builtin_amdgcn_exp2f(t01.x), __builtin_amdgcn_exp2f(t01.y)};
  f32x2 E1b = {__builtin_amdgcn_exp2f(t23.x), __builtin_amdgcn_exp2f(t23.y)};
  f32x2 E2a = E1a * E1a, E2b = E1b * E1b;      // alpha 0.25
  f32x2 E3a = E2a * E2a, E3b = E2b * E2b;      // alpha 0.5
  f32x2 E4a = E3a * E3a, E4b = E3b * E3b;      // alpha 1.0
  f32x2 E5a = E4a * E4a, E5b = E4b * E4b;      // alpha 2.0
  kva = ((E1a + E2a) + (E3a + E4a)) + E5a;
  kvb = ((E1b + E2b) + (E3b + E4b)) + E5b;
}

// ---------------- K1: self kernels (SS + QQ), 2 partials per pair ----------
__global__ __launch_bounds__(256, 4) void mmd_self_kernel(
    const float* __restrict__ sup, const float* __restrict__ qry,
    float* __restrict__ ws) {
  __shared__ short sbuf[NROW * C_];
  __shared__ float m2buf[NROW];
  __shared__ float redbuf[4];

  const int bid = blockIdx.x, tid = threadIdx.x;
  const int pair = bid >> 1, part = bid & 1;
  const float* xb = (pair < 20) ? sup + (size_t)pair * (NF_ * C_)
                                : qry + (size_t)(pair - 20) * (NF_ * C_);
  stage_bf16(xb, sbuf, tid);
  __syncthreads();
  m2_from_lds(sbuf, m2buf, tid);
  __syncthreads();

  const int w = tid >> 6, l = tid & 63;
  const int lr = l & 15, lg = l >> 4;
  const int dr = lr - lg * 4;                  // acc elem e hits diagonal iff e == dr
  const bool z0 = (dr == 0), z1 = (dr == 1), z2 = (dr == 2), z3 = (dr == 3);

  const int lo = part ? 85 : 0, hi = part ? NTT : 85;
  int t = lo + w;
  int ti = t / NTILE, tj = t - ti * NTILE;
  int curti = -1;
  short8 a0 = {0,0,0,0,0,0,0,0}, a1 = {0,0,0,0,0,0,0,0};
  f32x2 ms01 = {0.f, 0.f}, ms23 = {0.f, 0.f};
  f32x2 ksA = {0.f, 0.f}, ksB = {0.f, 0.f};

  while (t < hi) {
    if (ti != curti) {
      curti = ti;
      int ar = ti * 16 + lr, sw = (ar & 7) << 3;
      const short* ap = &sbuf[ar * C_];
      a0 = *(const short8*)&ap[((lg * 8) ^ sw)];
      a1 = *(const short8*)&ap[((32 + lg * 8) ^ sw)];
      f32x4 m4 = *(const f32x4*)&m2buf[ti * 16 + lg * 4];
      ms01.x = m4[0]; ms01.y = m4[1]; ms23.x = m4[2]; ms23.y = m4[3];
    }
    int br = tj * 16 + lr, swb = (br & 7) << 3;
    const short* bp = &sbuf[br * C_];
    short8 b0 = *(const short8*)&bp[((lg * 8) ^ swb)];
    short8 b1 = *(const short8*)&bp[((32 + lg * 8) ^ swb)];
    float m2q = m2buf[br];

    f32x4 acc = {0.f, 0.f, 0.f, 0.f};
    acc = __builtin_amdgcn_mfma_f32_16x16x32_bf16(a0, b0, acc, 0, 0, 0);
    acc = __builtin_amdgcn_mfma_f32_16x16x32_bf16(a1, b1, acc, 0, 0, 0);

    f32x2 kva, kvb;
    kpair(acc, ms01, ms23, m2q, kva, kvb);
    if (ti == tj) {                            // zero exact diagonal terms
      if (z0) kva.x = 0.f;
      if (z1) kva.y = 0.f;
      if (z2) kvb.x = 0.f;
      if (z3) kvb.y = 0.f;
    }
    ksA += kva; ksB += kvb;

    t += 4; tj += 4;
    if (tj >= NTILE) { tj -= NTILE; ++ti; }
  }

  float ks = (ksA.x + ksA.y) + (ksB.x + ksB.y);
#pragma unroll
  for (int off = 32; off > 0; off >>= 1) ks += __shfl_xor(ks, off);
  if (l == 0) redbuf[w] = ks;
  __syncthreads();
  if (tid == 0) {
    float s = (redbuf[0] + redbuf[1]) + (redbuf[2] + redbuf[3]);
    ws[bid] = s * (0.2f / (196.f * 195.f));    // pre-scaled partial
  }
}

// ---------------- K2: cross kernels (SQ), final output --------------------
__global__ __launch_bounds__(256, 4) void mmd_cross_kernel(
    const float* __restrict__ sup, const float* __restrict__ qry,
    const float* __restrict__ ws, float* __restrict__ out) {
  __shared__ short sbuf[NROW * C_];            // query bf16 swizzled
  __shared__ float m2q[NROW];                  // K2E*n2 per query row
  __shared__ float m2s[NROW];                  // K2E*n2 per support row
  __shared__ float redbuf[4];

  const int bid = blockIdx.x, tid = threadIdx.x;
  const int si = bid % 5;
  const int q = (bid / 5) % 75;
  const int b = bid / 375;
  const float* supb = sup + (size_t)(b * 5 + si) * (NF_ * C_);
  const float* qryb = qry + (size_t)(b * 75 + q) * (NF_ * C_);

  stage_bf16(qryb, sbuf, tid);
  if (tid < NROW) {                            // support m2 from global fp32
    float n2 = 1e30f;
    if (tid < NF_) {
      n2 = 0.f;
      const float4* s4 = (const float4*)(supb + tid * C_);
#pragma unroll
      for (int c = 0; c < 16; ++c) {
        float4 v = s4[c];
        float x;
        x = bf2f(f2bf(v.x)); n2 = fmaf(x, x, n2);
        x = bf2f(f2bf(v.y)); n2 = fmaf(x, x, n2);
        x = bf2f(f2bf(v.z)); n2 = fmaf(x, x, n2);
        x = bf2f(f2bf(v.w)); n2 = fmaf(x, x, n2);
      }
    }
    m2s[tid] = K2E_ * n2;
  }
  __syncthreads();
  m2_from_lds(sbuf, m2q, tid);
  __syncthreads();

  const int w = tid >> 6, l = tid & 63;
  const int lr = l & 15, lg = l >> 4;

  int t = w, ti = 0, tj = w;
  int curti = -1;
  short8 a0 = {0,0,0,0,0,0,0,0}, a1 = {0,0,0,0,0,0,0,0};
  f32x2 ms01 = {0.f, 0.f}, ms23 = {0.f, 0.f};
  f32x2 ksA = {0.f, 0.f}, ksB = {0.f, 0.f};

  while (t < NTT) {
    if (ti != curti) {
      curti = ti;
      int r = ti * 16 + lr;
      if (r < NF_) {                           // A-frag: global fp32 -> bf16 regs
        const float4* s4 = (const float4*)(supb + r * C_);
        a0 = pack8(s4[lg * 2], s4[lg * 2 + 1]);
        a1 = pack8(s4[8 + lg * 2], s4[8 + lg * 2 + 1]);
      } else {
        a0 = (short8){0,0,0,0,0,0,0,0};
        a1 = (short8){0,0,0,0,0,0,0,0};
      }
      f32x4 m4 = *(const f32x4*)&m2s[ti * 16 + lg * 4];
      ms01.x = m4[0]; ms01.y = m4[1]; ms23.x = m4[2]; ms23.y = m4[3];
    }
    int br = tj * 16 + lr, swb = (br & 7) << 3;
    const short* bp = &sbuf[br * C_];
    short8 b0 = *(const short8*)&bp[((lg * 8) ^ swb)];
    short8 b1 = *(const short8*)&bp[((32 + lg * 8) ^ swb)];
    float m2qv = m2q[br];

    f32x4 acc = {0.f, 0.f, 0.f, 0.f};
    acc = __builtin_amdgcn_mfma_f32_16x16x32_bf16(a0, b0, acc, 0, 0, 0);
    acc = __builtin_amdgcn_mfma_f32_16x16x32_bf16(a1, b1, acc, 0, 0, 0);

    f32x2 kva, kvb;
    kpair(acc, ms01, ms23, m2qv, kva, kvb);
    ksA += kva; ksB += kvb;

    t += 4; tj += 4;
    if (tj >= NTILE) { tj -= NTILE; ++ti; }
  }

  float ks = (ksA.x + ksA.y) + (ksB.x + ksB.y);
#pragma unroll
  for (int off = 32; off > 0; off >>= 1) ks += __shfl_xor(ks, off);
  if (l == 0) redbuf[w] = ks;
  __syncthreads();
  if (tid == 0) {
    float s = (redbuf[0] + redbuf[1]) + (redbuf[2] + redbuf[3]);
    float msq = s * (0.2f / (196.f * 196.f));
    int ps = (b * 5 + si) * 2;
    int pq = (20 + b * 75 + q) * 2;
    float mmd_s = ws[ps] + ws[ps + 1];
    float mmd_q = ws[pq] + ws[pq + 1];
    out[bid] = (mmd_s + mmd_q - 2.f * msq) * 12.5f;
  }
}

extern "C" void kernel_launch(void* const* d_in, const int* in_sizes, int n_in,
                              void* d_out, int out_size, void* d_ws, size_t ws_size,
                              hipStream_t stream) {
  const float* sup = (const float*)d_in[0];
  const float* qry = (const float*)d_in[1];
  float* out = (float*)d_out;
  float* ws = (float*)d_ws;  // 640 floats: partial mmd_s[20][2], mmd_q[300][2]

  mmd_self_kernel<<<dim3(640), dim3(256), 0, stream>>>(sup, qry, ws);
  mmd_cross_kernel<<<dim3(1500), dim3(256), 0, stream>>>(sup, qry, ws, out);
}

// Round 3
// 58.245 us; speedup vs baseline: 1.4690x; 1.4135x over previous
//
#include <hip/hip_runtime.h>

// MMDDistance: multi-scale Gaussian MMD.
// support [4,5,196,64] f32, query [4,75,196,64] f32 -> out [4,75,5] f32.
// alphas = 2^k, k=-3..1 -> exp chain via repeated squaring of exp(-0.125*d2).
//
// K1 (640 blocks): self-kernels SS (20) + QQ (300), 2 partials each, using
//     the k(i,j)=k(j,i) triangle (91 of 169 tiles; off-diag weight 2).
// K2 (1500 blocks): SQ cross-kernels, ti-outer/tj-inner walk with A-fragment
//     register prefetch (loads for ti+1 issued before the tj loop over ti),
//     query staged bf16 in LDS; writes final out.

typedef __attribute__((ext_vector_type(8))) short short8;
typedef __attribute__((ext_vector_type(4))) float f32x4;
typedef __attribute__((ext_vector_type(2))) float f32x2;

#define NF_  196
#define C_   64
#define NROW 208        // 13*16 padded rows
#define NTILE 13
#define NTT  (NTILE*NTILE)
#define NPAIR_TRI 91    // 13*14/2

#define K2E_  (-0.18033688011112042f)   // -0.125*log2(e)
#define NEG2K2E_ (0.36067376022224085f)

__device__ __forceinline__ short f2bf(float x) {
  unsigned u = __float_as_uint(x);
  u += 0x7fffu + ((u >> 16) & 1u);
  return (short)(u >> 16);
}
__device__ __forceinline__ float bf2f(short s) {
  return __uint_as_float(((unsigned)(unsigned short)s) << 16);
}
__device__ __forceinline__ short8 pack8(float4 a, float4 b) {
  short8 v;
  v[0] = f2bf(a.x); v[1] = f2bf(a.y); v[2] = f2bf(a.z); v[3] = f2bf(a.w);
  v[4] = f2bf(b.x); v[5] = f2bf(b.y); v[6] = f2bf(b.z); v[7] = f2bf(b.w);
  return v;
}

// stage one [196,64] fp32 array as bf16 into LDS, 16B-chunk XOR swizzle
__device__ __forceinline__ void stage_bf16(const float* __restrict__ src,
                                           short* __restrict__ sb, int tid) {
  for (int g = tid; g < NROW * 8; g += 256) {
    int row = g >> 3, c = g & 7;
    short8 v = {0, 0, 0, 0, 0, 0, 0, 0};
    if (row < NF_) {
      const float4* s4 = (const float4*)(src + row * C_ + c * 8);
      v = pack8(s4[0], s4[1]);
    }
    *(short8*)&sb[row * C_ + (((c * 8) ^ ((row & 7) << 3)))] = v;
  }
}

// m2[row] = K2E * sum(bf16(x)^2); pad rows -> K2E*1e30 (kernel value 0)
__device__ __forceinline__ void m2_from_lds(const short* __restrict__ sb,
                                            float* __restrict__ m2, int tid) {
  for (int row = tid; row < NROW; row += 256) {
    float acc = 1e30f;
    if (row < NF_) {
      acc = 0.f;
      int sw = (row & 7) << 3;
      const short* bp = &sb[row * C_];
#pragma unroll
      for (int c = 0; c < 8; ++c) {
        short8 vv = *(const short8*)&bp[((c * 8) ^ sw)];
#pragma unroll
        for (int e = 0; e < 8; ++e) { float x = bf2f(vv[e]); acc = fmaf(x, x, acc); }
      }
    }
    m2[row] = K2E_ * acc;
  }
}

// multi-gauss kernel values for 4 accumulator elems (two f32x2 pairs)
__device__ __forceinline__ void kpair(const f32x4 acc, f32x2 ms01, f32x2 ms23,
                                      float m2qv, f32x2& kva, f32x2& kvb) {
  f32x2 mq = {m2qv, m2qv};
  f32x2 a01 = {acc[0], acc[1]}, a23 = {acc[2], acc[3]};
  f32x2 zz = {0.f, 0.f};
  f32x2 t01 = a01 * NEG2K2E_ + (ms01 + mq);   // = K2E * d2
  f32x2 t23 = a23 * NEG2K2E_ + (ms23 + mq);
  t01 = __builtin_elementwise_min(t01, zz);
  t23 = __builtin_elementwise_min(t23, zz);
  f32x2 E1a = {__builtin_amdgcn_exp2f(t01.x), __builtin_amdgcn_exp2f(t01.y)};
  f32x2 E1b = {__builtin_amdgcn_exp2f(t23.x), __builtin_amdgcn_exp2f(t23.y)};
  f32x2 E2a = E1a * E1a, E2b = E1b * E1b;
  f32x2 E3a = E2a * E2a, E3b = E2b * E2b;
  f32x2 E4a = E3a * E3a, E4b = E3b * E3b;
  f32x2 E5a = E4a * E4a, E5b = E4b * E4b;
  kva = ((E1a + E2a) + (E3a + E4a)) + E5a;
  kvb = ((E1b + E2b) + (E3b + E4b)) + E5b;
}

// ---------------- K1: self kernels, triangle walk --------------------------
__global__ __launch_bounds__(256, 4) void mmd_self_kernel(
    const float* __restrict__ sup, const float* __restrict__ qry,
    float* __restrict__ ws) {
  __shared__ short sbuf[NROW * C_];
  __shared__ float m2buf[NROW];
  __shared__ float redbuf[4];

  const int bid = blockIdx.x, tid = threadIdx.x;
  const int pair = bid >> 1, part = bid & 1;
  const float* xb = (pair < 20) ? sup + (size_t)pair * (NF_ * C_)
                                : qry + (size_t)(pair - 20) * (NF_ * C_);
  stage_bf16(xb, sbuf, tid);
  __syncthreads();
  m2_from_lds(sbuf, m2buf, tid);
  __syncthreads();

  const int w = tid >> 6, l = tid & 63;
  const int lr = l & 15, lg = l >> 4;
  const int dr = lr - lg * 4;                 // acc elem e on diagonal iff e == dr
  const bool z0 = (dr == 0), z1 = (dr == 1), z2 = (dr == 2), z3 = (dr == 3);

  const int lo = part ? 45 : 0, hi = part ? NPAIR_TRI : 45;
  const int n = hi - lo;
  int p = lo + (n * w) / 4;
  const int pend = lo + (n * (w + 1)) / 4;

  // locate (ti,tj) of triangle pair index p (ti<=tj, ti-major)
  int ti = 0, off = 0;
  while (off + (NTILE - ti) <= p) { off += NTILE - ti; ++ti; }
  int tj = ti + (p - off);

  int curti = -1;
  short8 a0 = {0,0,0,0,0,0,0,0}, a1 = {0,0,0,0,0,0,0,0};
  f32x2 ms01 = {0.f, 0.f}, ms23 = {0.f, 0.f};
  f32x2 ksA = {0.f, 0.f}, ksB = {0.f, 0.f};   // off-diagonal tiles (weight 2)
  f32x2 kdA = {0.f, 0.f}, kdB = {0.f, 0.f};   // diagonal tiles   (weight 1)

  for (; p < pend; ++p) {
    if (ti != curti) {
      curti = ti;
      int ar = ti * 16 + lr, sw = (ar & 7) << 3;
      const short* ap = &sbuf[ar * C_];
      a0 = *(const short8*)&ap[((lg * 8) ^ sw)];
      a1 = *(const short8*)&ap[((32 + lg * 8) ^ sw)];
      f32x4 m4 = *(const f32x4*)&m2buf[ti * 16 + lg * 4];
      ms01.x = m4[0]; ms01.y = m4[1]; ms23.x = m4[2]; ms23.y = m4[3];
    }
    int br = tj * 16 + lr, swb = (br & 7) << 3;
    const short* bp = &sbuf[br * C_];
    short8 b0 = *(const short8*)&bp[((lg * 8) ^ swb)];
    short8 b1 = *(const short8*)&bp[((32 + lg * 8) ^ swb)];
    float m2q = m2buf[br];

    f32x4 acc = {0.f, 0.f, 0.f, 0.f};
    acc = __builtin_amdgcn_mfma_f32_16x16x32_bf16(a0, b0, acc, 0, 0, 0);
    acc = __builtin_amdgcn_mfma_f32_16x16x32_bf16(a1, b1, acc, 0, 0, 0);

    f32x2 kva, kvb;
    kpair(acc, ms01, ms23, m2q, kva, kvb);
    if (ti == tj) {
      if (z0) kva.x = 0.f;
      if (z1) kva.y = 0.f;
      if (z2) kvb.x = 0.f;
      if (z3) kvb.y = 0.f;
      kdA += kva; kdB += kvb;
    } else {
      ksA += kva; ksB += kvb;
    }
    ++tj;
    if (tj == NTILE) { ++ti; tj = ti; }
  }

  float ks = 2.f * ((ksA.x + ksA.y) + (ksB.x + ksB.y))
           + ((kdA.x + kdA.y) + (kdB.x + kdB.y));
#pragma unroll
  for (int o = 32; o > 0; o >>= 1) ks += __shfl_xor(ks, o);
  if (l == 0) redbuf[w] = ks;
  __syncthreads();
  if (tid == 0) {
    float s = (redbuf[0] + redbuf[1]) + (redbuf[2] + redbuf[3]);
    ws[bid] = s * (0.2f / (196.f * 195.f));
  }
}

// ---------------- K2: cross kernels, ti-outer + A prefetch ----------------
__global__ __launch_bounds__(256, 4) void mmd_cross_kernel(
    const float* __restrict__ sup, const float* __restrict__ qry,
    const float* __restrict__ ws, float* __restrict__ out) {
  __shared__ short sbuf[NROW * C_];            // query bf16 swizzled
  __shared__ float m2q[NROW];
  __shared__ float m2s[NROW];
  __shared__ float redbuf[4];

  const int bid = blockIdx.x, tid = threadIdx.x;
  const int si = bid % 5;
  const int q = (bid / 5) % 75;
  const int b = bid / 375;
  const float* supb = sup + (size_t)(b * 5 + si) * (NF_ * C_);
  const float* qryb = qry + (size_t)(b * 75 + q) * (NF_ * C_);

  stage_bf16(qryb, sbuf, tid);
  if (tid < NROW) {
    float n2 = 1e30f;
    if (tid < NF_) {
      n2 = 0.f;
      const float4* s4 = (const float4*)(supb + tid * C_);
#pragma unroll
      for (int c = 0; c < 16; ++c) {
        float4 v = s4[c];
        float x;
        x = bf2f(f2bf(v.x)); n2 = fmaf(x, x, n2);
        x = bf2f(f2bf(v.y)); n2 = fmaf(x, x, n2);
        x = bf2f(f2bf(v.z)); n2 = fmaf(x, x, n2);
        x = bf2f(f2bf(v.w)); n2 = fmaf(x, x, n2);
      }
    }
    m2s[tid] = K2E_ * n2;
  }
  __syncthreads();
  m2_from_lds(sbuf, m2q, tid);
  __syncthreads();

  const int w = tid >> 6, l = tid & 63;
  const int lr = l & 15, lg = l >> 4;

  const int p0i = (NTT * w) / 4, p1i = (NTT * (w + 1)) / 4;
  int t = p0i;
  int ti = t / NTILE, tj = t - ti * NTILE;

  // issue first A-fragment loads (support rows from global fp32)
  float4 f0 = {0,0,0,0}, f1 = {0,0,0,0}, f2 = {0,0,0,0}, f3 = {0,0,0,0};
  {
    int r = ti * 16 + lr;
    if (r < NF_) {
      const float4* s4 = (const float4*)(supb + r * C_);
      f0 = s4[lg * 2]; f1 = s4[lg * 2 + 1];
      f2 = s4[8 + lg * 2]; f3 = s4[8 + lg * 2 + 1];
    }
  }

  short8 a0, a1;
  f32x2 ms01, ms23;
  f32x2 ksA = {0.f, 0.f}, ksB = {0.f, 0.f};

  while (t < p1i) {
    // consume prefetched A (waitcnt lands here), then prefetch next ti
    a0 = pack8(f0, f1);
    a1 = pack8(f2, f3);
    {
      f32x4 m4 = *(const f32x4*)&m2s[ti * 16 + lg * 4];
      ms01.x = m4[0]; ms01.y = m4[1]; ms23.x = m4[2]; ms23.y = m4[3];
    }
    int nj = NTILE - tj;
    if (nj > p1i - t) nj = p1i - t;
    if (t + nj < p1i) {
      int r = (ti + 1) * 16 + lr;
      if (r < NF_) {
        const float4* s4 = (const float4*)(supb + r * C_);
        f0 = s4[lg * 2]; f1 = s4[lg * 2 + 1];
        f2 = s4[8 + lg * 2]; f3 = s4[8 + lg * 2 + 1];
      } else {
        f0 = f1 = f2 = f3 = (float4){0, 0, 0, 0};
      }
    }

    auto body = [&](int tjv) {
      int br = tjv * 16 + lr, swb = (br & 7) << 3;
      const short* bp = &sbuf[br * C_];
      short8 b0 = *(const short8*)&bp[((lg * 8) ^ swb)];
      short8 b1 = *(const short8*)&bp[((32 + lg * 8) ^ swb)];
      float m2qv = m2q[br];
      f32x4 acc = {0.f, 0.f, 0.f, 0.f};
      acc = __builtin_amdgcn_mfma_f32_16x16x32_bf16(a0, b0, acc, 0, 0, 0);
      acc = __builtin_amdgcn_mfma_f32_16x16x32_bf16(a1, b1, acc, 0, 0, 0);
      f32x2 kva, kvb;
      kpair(acc, ms01, ms23, m2qv, kva, kvb);
      ksA += kva; ksB += kvb;
    };

    if (nj == NTILE) {
#pragma unroll
      for (int jj = 0; jj < NTILE; ++jj) body(jj);
    } else {
      for (int jj = 0; jj < nj; ++jj) body(tj + jj);
    }

    t += nj; tj = 0; ++ti;
  }

  float ks = (ksA.x + ksA.y) + (ksB.x + ksB.y);
#pragma unroll
  for (int o = 32; o > 0; o >>= 1) ks += __shfl_xor(ks, o);
  if (l == 0) redbuf[w] = ks;
  __syncthreads();
  if (tid == 0) {
    float s = (redbuf[0] + redbuf[1]) + (redbuf[2] + redbuf[3]);
    float msq = s * (0.2f / (196.f * 196.f));
    int ps = (b * 5 + si) * 2;
    int pq = (20 + b * 75 + q) * 2;
    float mmd_s = ws[ps] + ws[ps + 1];
    float mmd_q = ws[pq] + ws[pq + 1];
    out[bid] = (mmd_s + mmd_q - 2.f * msq) * 12.5f;
  }
}

extern "C" void kernel_launch(void* const* d_in, const int* in_sizes, int n_in,
                              void* d_out, int out_size, void* d_ws, size_t ws_size,
                              hipStream_t stream) {
  const float* sup = (const float*)d_in[0];
  const float* qry = (const float*)d_in[1];
  float* out = (float*)d_out;
  float* ws = (float*)d_ws;  // 640 floats: partial mmd_s[20][2], mmd_q[300][2]

  mmd_self_kernel<<<dim3(640), dim3(256), 0, stream>>>(sup, qry, ws);
  mmd_cross_kernel<<<dim3(1500), dim3(256), 0, stream>>>(sup, qry, ws, out);
}